// Round 9
// baseline (500.594 us; speedup 1.0000x reference)
//
#include <hip/hip_runtime.h>
#include <hip/hip_bf16.h>
#include <stdint.h>

typedef __bf16 bf16_t;
typedef __bf16 bf16x8 __attribute__((ext_vector_type(8)));
typedef float f32x16 __attribute__((ext_vector_type(16)));
typedef float f32x4v __attribute__((ext_vector_type(4)));   // native vec for nontemporal

#define BB 8
#define KK 1024
#define LL 1024
#define DD 1024
#define OO 6
#define EE 128
#define NN 768   // OO*EE

// ---------------------------------------------------------------------------
__device__ __forceinline__ void async_copy16(const void* gptr, void* lds) {
    __builtin_amdgcn_global_load_lds(
        (__attribute__((address_space(1))) void*)gptr,
        (__attribute__((address_space(3))) void*)lds,
        16, 0, 0);
}

__device__ __forceinline__ void split_bf16(float x, bf16_t& hi, bf16_t& lo) {
    hi = (bf16_t)x;
    lo = (bf16_t)(x - (float)hi);
}

// squash helper: sp[12] (slot s = element s*64+lane of a 768-row) -> vv[12].
__device__ __forceinline__ void squash_regs(const float* sp, float* vv, int lane) {
#pragma unroll
    for (int o = 0; o < 6; ++o) {
        float t = sp[2*o]*sp[2*o] + sp[2*o+1]*sp[2*o+1];
#pragma unroll
        for (int off = 32; off > 0; off >>= 1) t += __shfl_xor(t, off, 64);
        const float sc = t / (1.0f + t) / (sqrtf(t) + 1e-8f);
        vv[2*o]   = sc * sp[2*o];
        vv[2*o+1] = sc * sp[2*o+1];
    }
}

// ---------------------------------------------------------------------------
// Fused prep: [0,8192) convert A; [8192,8960) transpose+convert W;
// [8960,8969) zero sbuf (3*8*768 floats).
__global__ __launch_bounds__(256) void prep_kernel(
    const float* __restrict__ A, bf16_t* __restrict__ Ah, bf16_t* __restrict__ Al,
    const float* __restrict__ W, bf16_t* __restrict__ Wth, bf16_t* __restrict__ Wtl,
    float* __restrict__ sbuf)
{
    const int bx = blockIdx.x;
    if (bx < 8192) {
        const long i = ((long)bx * 256 + threadIdx.x) * 4;
        const float4 x = *(const float4*)(A + i);
        union { bf16_t h[4]; uint2 u; } ph, pl;
        split_bf16(x.x, ph.h[0], pl.h[0]);
        split_bf16(x.y, ph.h[1], pl.h[1]);
        split_bf16(x.z, ph.h[2], pl.h[2]);
        split_bf16(x.w, ph.h[3], pl.h[3]);
        *(uint2*)(Ah + i) = ph.u;
        *(uint2*)(Al + i) = pl.u;
    } else if (bx < 8960) {
        __shared__ float t[32][33];
        const int flat = bx - 8192;          // 0..767
        const int o  = flat / 128;
        const int rem = flat % 128;
        const int d0 = (rem & 31) * 32;
        const int e0 = (rem >> 5) * 32;
        const int tx = threadIdx.x & 31;
        const int ty = threadIdx.x >> 5;
        const float* Wo = W + (long)o * DD * EE;
        bf16_t* Ho = Wth + (long)o * EE * DD;
        bf16_t* Lo = Wtl + (long)o * EE * DD;
#pragma unroll
        for (int p = 0; p < 4; ++p)
            t[p * 8 + ty][tx] = Wo[(long)(d0 + p * 8 + ty) * EE + e0 + tx];
        __syncthreads();
#pragma unroll
        for (int p = 0; p < 4; ++p) {
            const float val = t[tx][p * 8 + ty];
            bf16_t h, l;
            split_bf16(val, h, l);
            const long idx = (long)(e0 + p * 8 + ty) * DD + d0 + tx;
            Ho[idx] = h;
            Lo[idx] = l;
        }
    } else {
#pragma unroll
        for (int r = 0; r < 4; ++r) {
            const int idx = (bx - 8960) * 1024 + r * 256 + threadIdx.x;
            if (idx < 3 * BB * NN) sbuf[idx] = 0.f;
        }
    }
}

// ---------------------------------------------------------------------------
// priors GEMM (3-term bf16 split) using mfma_f32_32x32x16_bf16.
// 128x64 tile, BK=32, 1-D grid 768 XCD-swizzled (bn fast within an XCD).
__global__ __launch_bounds__(256) void gemm_priors(
    const bf16_t* __restrict__ Ah, const bf16_t* __restrict__ Al,
    const bf16_t* __restrict__ Bh, const bf16_t* __restrict__ Bl,
    float* __restrict__ C, float* __restrict__ s0)
{
    __shared__ alignas(16) bf16_t sAh[128 * 32];
    __shared__ alignas(16) bf16_t sAl[128 * 32];
    __shared__ alignas(16) bf16_t sBh[64 * 32];
    __shared__ alignas(16) bf16_t sBl[64 * 32];
    __shared__ float sRed[64];

    const int bid  = blockIdx.x;
    const int xcd  = bid & 7;
    const int sgp  = bid >> 3;              // 0..95
    const int bn   = sgp % 12;
    const int bm   = (sgp / 12) * 8 + xcd;  // 0..63

    const int tid  = threadIdx.x;
    const int w    = tid >> 6;
    const int lane = tid & 63;
    const int qr   = (w >> 1) * 64;
    const int qc   = (w & 1) * 32;
    const int l31  = lane & 31;
    const int lh   = lane >> 5;             // 0/1

    f32x16 acc[2] = {};

    const int mrowA = w * 32 + (lane >> 2);
    const int mrowB = w * 16 + (lane >> 2);
    const int kcol  = (lane & 3) * 8;

    const long aoff = (long)(bm * 128 + mrowA) * DD + kcol;
    const long boff = (long)(bn * 64  + mrowB) * DD + kcol;
    const bf16_t* gAh0 = Ah + aoff;  const bf16_t* gAh1 = gAh0 + 16 * DD;
    const bf16_t* gAl0 = Al + aoff;  const bf16_t* gAl1 = gAl0 + 16 * DD;
    const bf16_t* gBh  = Bh + boff;
    const bf16_t* gBl  = Bl + boff;

    bf16_t* lAh0 = sAh + (w * 2 + 0) * 512;
    bf16_t* lAh1 = sAh + (w * 2 + 1) * 512;
    bf16_t* lAl0 = sAl + (w * 2 + 0) * 512;
    bf16_t* lAl1 = sAl + (w * 2 + 1) * 512;
    bf16_t* lBh  = sBh + w * 512;
    bf16_t* lBl  = sBl + w * 512;

    for (int kt = 0; kt < DD / 32; ++kt) {
        const int k0 = kt * 32;
        async_copy16(gAh0 + k0, lAh0);
        async_copy16(gAh1 + k0, lAh1);
        async_copy16(gAl0 + k0, lAl0);
        async_copy16(gAl1 + k0, lAl1);
        async_copy16(gBh  + k0, lBh);
        async_copy16(gBl  + k0, lBl);
        __syncthreads();

#pragma unroll
        for (int kh = 0; kh < 2; ++kh) {
            const int kb = kh * 16 + lh * 8;
            bf16x8 ahf[2], alf[2], bhf, blf;
#pragma unroll
            for (int i = 0; i < 2; ++i) {
                const int ra = (qr + i * 32 + l31) * 32 + kb;
                ahf[i] = *(const bf16x8*)(sAh + ra);
                alf[i] = *(const bf16x8*)(sAl + ra);
            }
            const int rb = (qc + l31) * 32 + kb;
            bhf = *(const bf16x8*)(sBh + rb);
            blf = *(const bf16x8*)(sBl + rb);
#pragma unroll
            for (int i = 0; i < 2; ++i) {
                acc[i] = __builtin_amdgcn_mfma_f32_32x32x16_bf16(
                    alf[i], bhf, acc[i], 0, 0, 0);
                acc[i] = __builtin_amdgcn_mfma_f32_32x32x16_bf16(
                    ahf[i], blf, acc[i], 0, 0, 0);
                acc[i] = __builtin_amdgcn_mfma_f32_32x32x16_bf16(
                    ahf[i], bhf, acc[i], 0, 0, 0);
            }
        }
        __syncthreads();
    }

    // C store. 32x32 C/D: col = lane&31, row = (r&3)+8*(r>>2)+4*(lane>>5)
    const int col = bn * 64 + qc + l31;
#pragma unroll
    for (int i = 0; i < 2; ++i) {
#pragma unroll
        for (int r = 0; r < 16; ++r) {
            const int row = bm * 128 + qr + i * 32 + (r & 3) + 8 * (r >> 2) + 4 * lh;
            C[(long)row * NN + col] = acc[i][r];
        }
    }

    // iter-0 s epilogue: column sums over this block's 128 rows (b = bm>>3).
    if (tid < 64) sRed[tid] = 0.f;
    __syncthreads();
    float cs = 0.f;
#pragma unroll
    for (int i = 0; i < 2; ++i)
#pragma unroll
        for (int r = 0; r < 16; ++r) cs += acc[i][r];
    cs += __shfl_xor(cs, 32, 64);
    if (lane < 32) atomicAdd(&sRed[qc + l31], cs);
    __syncthreads();
    if (tid < 64)
        atomicAdd(&s0[(bm >> 3) * NN + bn * 64 + tid], sRed[tid] * (1.0f / 6.0f));
}

// ---------------------------------------------------------------------------
// Fused routing step: v = squash(s_prev); per (b,k): delta = priors.v;
// g' = (first ? delta : g+delta); p = mask ? 1/6 : softmax(g');
// s_cur += p * priors. If outP != null (last iter): broadcast p over L into
// the output's P-section directly (nontemporal). grid 1024.
__global__ __launch_bounds__(256) void pgs_kernel(
    const float* __restrict__ priors, const float* __restrict__ s_prev,
    const int* __restrict__ mask, float* __restrict__ g,
    float* __restrict__ s_cur, float* __restrict__ outP, int first)
{
    const int blk  = blockIdx.x;
    const int b    = blk >> 7;
    const int k8   = (blk & 127) * 8;
    const int w    = threadIdx.x >> 6;
    const int lane = threadIdx.x & 63;

    __shared__ float red[4][768];
    __shared__ float pstage[48];

    float vv[12];
    {
        float sp[12];
#pragma unroll
        for (int s = 0; s < 12; ++s) sp[s] = s_prev[b * NN + s * 64 + lane];
        squash_regs(sp, vv, lane);
    }

    float sacc[12];
#pragma unroll
    for (int s = 0; s < 12; ++s) sacc[s] = 0.f;

#pragma unroll
    for (int r = 0; r < 2; ++r) {
        const int k = k8 + w * 2 + r;
        const long rid = (long)b * KK + k;
        const float* pr = priors + rid * NN;
        float pp[12];
#pragma unroll
        for (int s = 0; s < 12; ++s) pp[s] = pr[s * 64 + lane];

        float d[6];
#pragma unroll
        for (int o = 0; o < 6; ++o) {
            float t = pp[2*o] * vv[2*o] + pp[2*o+1] * vv[2*o+1];
#pragma unroll
            for (int off = 32; off > 0; off >>= 1) t += __shfl_xor(t, off, 64);
            d[o] = t;
        }

        if (first) {
            if (lane < 6) {
                float x = d[0];
#pragma unroll
                for (int o = 1; o < 6; ++o) if (lane == o) x = d[o];
                g[rid * 6 + lane] = x;
            }
        } else {
#pragma unroll
            for (int o = 0; o < 6; ++o) d[o] += g[rid * 6 + o];
        }

        float p[6];
        if (mask[rid] != 0) {
#pragma unroll
            for (int o = 0; o < 6; ++o) p[o] = 1.0f / 6.0f;
        } else {
            float m = d[0];
#pragma unroll
            for (int o = 1; o < 6; ++o) m = fmaxf(m, d[o]);
            float ssum = 0.f;
#pragma unroll
            for (int o = 0; o < 6; ++o) { p[o] = expf(d[o] - m); ssum += p[o]; }
            const float inv = 1.0f / ssum;
#pragma unroll
            for (int o = 0; o < 6; ++o) p[o] *= inv;
        }

        if (outP && lane < 6) {
            float x = p[0];
#pragma unroll
            for (int o = 1; o < 6; ++o) if (lane == o) x = p[o];
            pstage[(w * 2 + r) * 6 + lane] = x;
        }

#pragma unroll
        for (int s = 0; s < 12; ++s) sacc[s] = fmaf(p[s >> 1], pp[s], sacc[s]);
    }

#pragma unroll
    for (int s = 0; s < 12; ++s) red[w][s * 64 + lane] = sacc[s];
    __syncthreads();
    const int t = threadIdx.x;
#pragma unroll
    for (int i = 0; i < 3; ++i) {
        const int flat = t + i * 256;
        atomicAdd(&s_cur[b * NN + flat],
                  red[0][flat] + red[1][flat] + red[2][flat] + red[3][flat]);
    }

    if (outP) {
        // broadcast this block's 48 probs (8 k x 6 o) to all 1024 l positions.
        float* base = outP + (long)b * (LL * KK * OO) + k8 * 6;
        const int j = t & 3;
        const int lsub = t >> 2;
        const f32x4v c0 = *(const f32x4v*)(pstage + j * 12);
        const f32x4v c1 = *(const f32x4v*)(pstage + j * 12 + 4);
        const f32x4v c2 = *(const f32x4v*)(pstage + j * 12 + 8);
#pragma unroll
        for (int lg = 0; lg < 16; ++lg) {
            float* dst = base + (long)(lg * 64 + lsub) * (KK * OO) + j * 12;
            __builtin_nontemporal_store(c0, (f32x4v*)(dst));
            __builtin_nontemporal_store(c1, (f32x4v*)(dst + 4));
            __builtin_nontemporal_store(c2, (f32x4v*)(dst + 8));
        }
    }
}

// ---------------------------------------------------------------------------
// Output V-section: squash(s2) broadcast over L (nontemporal). grid 2048.
__global__ __launch_bounds__(256) void bcast_v_kernel(
    const float* __restrict__ s2, float* __restrict__ out)
{
    const int blk = blockIdx.x;
    const int b  = blk >> 8;
    const int l0 = (blk & 255) * 4;
    const int w = threadIdx.x >> 6, lane = threadIdx.x & 63;
    __shared__ float vrow[768];
    if (w == 0) {
        float sp[12], vvv[12];
#pragma unroll
        for (int s = 0; s < 12; ++s) sp[s] = s2[b * NN + s * 64 + lane];
        squash_regs(sp, vvv, lane);
#pragma unroll
        for (int s = 0; s < 12; ++s) vrow[s * 64 + lane] = vvv[s];
    }
    __syncthreads();
    float* dst = out + ((long)b * LL + l0) * NN;
    const int t = threadIdx.x;
#pragma unroll
    for (int i = 0; i < 3; ++i) {
        const int idx = t * 12 + i * 4;
        const f32x4v val = *(const f32x4v*)(vrow + (idx % NN));
        __builtin_nontemporal_store(val, (f32x4v*)(dst + idx));
    }
}

// ---------------------------------------------------------------------------
extern "C" void kernel_launch(void* const* d_in, const int* in_sizes, int n_in,
                              void* d_out, int out_size, void* d_ws, size_t ws_size,
                              hipStream_t stream)
{
    (void)in_sizes; (void)n_in; (void)out_size; (void)ws_size;
    const float* u    = (const float*)d_in[0];
    const float* W    = (const float*)d_in[2];
    const int*   mask = (const int*)d_in[3];
    float*       out  = (float*)d_out;

    char* ws = (char*)d_ws;
    size_t off = 0;
    float*  priors = (float*)(ws + off);  off += (size_t)8192 * NN * 4;
    bf16_t* Ah     = (bf16_t*)(ws + off); off += (size_t)8192 * DD * 2;
    bf16_t* Al     = (bf16_t*)(ws + off); off += (size_t)8192 * DD * 2;
    bf16_t* Wth    = (bf16_t*)(ws + off); off += (size_t)OO * EE * DD * 2;
    bf16_t* Wtl    = (bf16_t*)(ws + off); off += (size_t)OO * EE * DD * 2;
    float*  g      = (float*)(ws + off);  off += (size_t)BB * KK * OO * 4;
    float*  sbuf   = (float*)(ws + off);  off += (size_t)3 * BB * NN * 4;
    float*  s0 = sbuf, *s1 = sbuf + BB * NN, *s2 = sbuf + 2 * BB * NN;

    const long NVF = (long)BB * LL * OO * EE;   // V-section size = 6,291,456

    hipLaunchKernelGGL(prep_kernel, dim3(8969), dim3(256), 0, stream,
                       u, Ah, Al, W, Wth, Wtl, sbuf);
    hipLaunchKernelGGL(gemm_priors, dim3(768), dim3(256), 0, stream,
                       Ah, Al, Wth, Wtl, priors, s0);
    hipLaunchKernelGGL(pgs_kernel, dim3(1024), dim3(256), 0, stream,
                       priors, s0, mask, g, s1, (float*)nullptr, 1);
    hipLaunchKernelGGL(pgs_kernel, dim3(1024), dim3(256), 0, stream,
                       priors, s1, mask, g, s2, out + NVF, 0);
    hipLaunchKernelGGL(bcast_v_kernel, dim3(2048), dim3(256), 0, stream,
                       s2, out);
}

// Round 10
// 365.597 us; speedup vs baseline: 1.3693x; 1.3693x over previous
//
#include <hip/hip_runtime.h>
#include <hip/hip_bf16.h>
#include <stdint.h>

typedef __bf16 bf16_t;
typedef __bf16 bf16x8 __attribute__((ext_vector_type(8)));
typedef float f32x16 __attribute__((ext_vector_type(16)));

#define BB 8
#define KK 1024
#define LL 1024
#define DD 1024
#define OO 6
#define EE 128
#define NN 768   // OO*EE

// ---------------------------------------------------------------------------
__device__ __forceinline__ void async_copy16(const void* gptr, void* lds) {
    __builtin_amdgcn_global_load_lds(
        (__attribute__((address_space(1))) void*)gptr,
        (__attribute__((address_space(3))) void*)lds,
        16, 0, 0);
}

__device__ __forceinline__ void split_bf16(float x, bf16_t& hi, bf16_t& lo) {
    hi = (bf16_t)x;
    lo = (bf16_t)(x - (float)hi);
}

// squash helper: sp[12] (slot s = element s*64+lane of a 768-row) -> vv[12].
__device__ __forceinline__ void squash_regs(const float* sp, float* vv, int lane) {
#pragma unroll
    for (int o = 0; o < 6; ++o) {
        float t = sp[2*o]*sp[2*o] + sp[2*o+1]*sp[2*o+1];
#pragma unroll
        for (int off = 32; off > 0; off >>= 1) t += __shfl_xor(t, off, 64);
        const float sc = t / (1.0f + t) / (sqrtf(t) + 1e-8f);
        vv[2*o]   = sc * sp[2*o];
        vv[2*o+1] = sc * sp[2*o+1];
    }
}

// ---------------------------------------------------------------------------
// Fused prep: [0,8192) convert A; [8192,8960) transpose+convert W;
// [8960,8969) zero sbuf (3*8*768 floats).
__global__ __launch_bounds__(256) void prep_kernel(
    const float* __restrict__ A, bf16_t* __restrict__ Ah, bf16_t* __restrict__ Al,
    const float* __restrict__ W, bf16_t* __restrict__ Wth, bf16_t* __restrict__ Wtl,
    float* __restrict__ sbuf)
{
    const int bx = blockIdx.x;
    if (bx < 8192) {
        const long i = ((long)bx * 256 + threadIdx.x) * 4;
        const float4 x = *(const float4*)(A + i);
        union { bf16_t h[4]; uint2 u; } ph, pl;
        split_bf16(x.x, ph.h[0], pl.h[0]);
        split_bf16(x.y, ph.h[1], pl.h[1]);
        split_bf16(x.z, ph.h[2], pl.h[2]);
        split_bf16(x.w, ph.h[3], pl.h[3]);
        *(uint2*)(Ah + i) = ph.u;
        *(uint2*)(Al + i) = pl.u;
    } else if (bx < 8960) {
        __shared__ float t[32][33];
        const int flat = bx - 8192;          // 0..767
        const int o  = flat / 128;
        const int rem = flat % 128;
        const int d0 = (rem & 31) * 32;
        const int e0 = (rem >> 5) * 32;
        const int tx = threadIdx.x & 31;
        const int ty = threadIdx.x >> 5;
        const float* Wo = W + (long)o * DD * EE;
        bf16_t* Ho = Wth + (long)o * EE * DD;
        bf16_t* Lo = Wtl + (long)o * EE * DD;
#pragma unroll
        for (int p = 0; p < 4; ++p)
            t[p * 8 + ty][tx] = Wo[(long)(d0 + p * 8 + ty) * EE + e0 + tx];
        __syncthreads();
#pragma unroll
        for (int p = 0; p < 4; ++p) {
            const float val = t[tx][p * 8 + ty];
            bf16_t h, l;
            split_bf16(val, h, l);
            const long idx = (long)(e0 + p * 8 + ty) * DD + d0 + tx;
            Ho[idx] = h;
            Lo[idx] = l;
        }
    } else {
#pragma unroll
        for (int r = 0; r < 4; ++r) {
            const int idx = (bx - 8960) * 1024 + r * 256 + threadIdx.x;
            if (idx < 3 * BB * NN) sbuf[idx] = 0.f;
        }
    }
}

// ---------------------------------------------------------------------------
// priors GEMM (3-term bf16 split) using mfma_f32_32x32x16_bf16.
// 128x64 tile, BK=32, 1-D grid 768 XCD-swizzled (bn fast within an XCD).
__global__ __launch_bounds__(256) void gemm_priors(
    const bf16_t* __restrict__ Ah, const bf16_t* __restrict__ Al,
    const bf16_t* __restrict__ Bh, const bf16_t* __restrict__ Bl,
    float* __restrict__ C, float* __restrict__ s0)
{
    __shared__ alignas(16) bf16_t sAh[128 * 32];
    __shared__ alignas(16) bf16_t sAl[128 * 32];
    __shared__ alignas(16) bf16_t sBh[64 * 32];
    __shared__ alignas(16) bf16_t sBl[64 * 32];
    __shared__ float sRed[64];

    const int bid  = blockIdx.x;
    const int xcd  = bid & 7;
    const int sgp  = bid >> 3;              // 0..95
    const int bn   = sgp % 12;
    const int bm   = (sgp / 12) * 8 + xcd;  // 0..63

    const int tid  = threadIdx.x;
    const int w    = tid >> 6;
    const int lane = tid & 63;
    const int qr   = (w >> 1) * 64;
    const int qc   = (w & 1) * 32;
    const int l31  = lane & 31;
    const int lh   = lane >> 5;             // 0/1

    f32x16 acc[2] = {};

    const int mrowA = w * 32 + (lane >> 2);
    const int mrowB = w * 16 + (lane >> 2);
    const int kcol  = (lane & 3) * 8;

    const long aoff = (long)(bm * 128 + mrowA) * DD + kcol;
    const long boff = (long)(bn * 64  + mrowB) * DD + kcol;
    const bf16_t* gAh0 = Ah + aoff;  const bf16_t* gAh1 = gAh0 + 16 * DD;
    const bf16_t* gAl0 = Al + aoff;  const bf16_t* gAl1 = gAl0 + 16 * DD;
    const bf16_t* gBh  = Bh + boff;
    const bf16_t* gBl  = Bl + boff;

    bf16_t* lAh0 = sAh + (w * 2 + 0) * 512;
    bf16_t* lAh1 = sAh + (w * 2 + 1) * 512;
    bf16_t* lAl0 = sAl + (w * 2 + 0) * 512;
    bf16_t* lAl1 = sAl + (w * 2 + 1) * 512;
    bf16_t* lBh  = sBh + w * 512;
    bf16_t* lBl  = sBl + w * 512;

    for (int kt = 0; kt < DD / 32; ++kt) {
        const int k0 = kt * 32;
        async_copy16(gAh0 + k0, lAh0);
        async_copy16(gAh1 + k0, lAh1);
        async_copy16(gAl0 + k0, lAl0);
        async_copy16(gAl1 + k0, lAl1);
        async_copy16(gBh  + k0, lBh);
        async_copy16(gBl  + k0, lBl);
        __syncthreads();

#pragma unroll
        for (int kh = 0; kh < 2; ++kh) {
            const int kb = kh * 16 + lh * 8;
            bf16x8 ahf[2], alf[2], bhf, blf;
#pragma unroll
            for (int i = 0; i < 2; ++i) {
                const int ra = (qr + i * 32 + l31) * 32 + kb;
                ahf[i] = *(const bf16x8*)(sAh + ra);
                alf[i] = *(const bf16x8*)(sAl + ra);
            }
            const int rb = (qc + l31) * 32 + kb;
            bhf = *(const bf16x8*)(sBh + rb);
            blf = *(const bf16x8*)(sBl + rb);
#pragma unroll
            for (int i = 0; i < 2; ++i) {
                acc[i] = __builtin_amdgcn_mfma_f32_32x32x16_bf16(
                    alf[i], bhf, acc[i], 0, 0, 0);
                acc[i] = __builtin_amdgcn_mfma_f32_32x32x16_bf16(
                    ahf[i], blf, acc[i], 0, 0, 0);
                acc[i] = __builtin_amdgcn_mfma_f32_32x32x16_bf16(
                    ahf[i], bhf, acc[i], 0, 0, 0);
            }
        }
        __syncthreads();
    }

    // C store. 32x32 C/D: col = lane&31, row = (r&3)+8*(r>>2)+4*(lane>>5)
    const int col = bn * 64 + qc + l31;
#pragma unroll
    for (int i = 0; i < 2; ++i) {
#pragma unroll
        for (int r = 0; r < 16; ++r) {
            const int row = bm * 128 + qr + i * 32 + (r & 3) + 8 * (r >> 2) + 4 * lh;
            C[(long)row * NN + col] = acc[i][r];
        }
    }

    // iter-0 s epilogue: column sums over this block's 128 rows (b = bm>>3).
    if (tid < 64) sRed[tid] = 0.f;
    __syncthreads();
    float cs = 0.f;
#pragma unroll
    for (int i = 0; i < 2; ++i)
#pragma unroll
        for (int r = 0; r < 16; ++r) cs += acc[i][r];
    cs += __shfl_xor(cs, 32, 64);
    if (lane < 32) atomicAdd(&sRed[qc + l31], cs);
    __syncthreads();
    if (tid < 64)
        atomicAdd(&s0[(bm >> 3) * NN + bn * 64 + tid], sRed[tid] * (1.0f / 6.0f));
}

// ---------------------------------------------------------------------------
// Fused routing step: v = squash(s_prev); per (b,k): delta = priors.v;
// g' = (first ? delta : g+delta); p = mask ? 1/6 : softmax(g');
// s_cur += p * priors. If outP != null (last iter): broadcast p over L into
// the output's P-section directly (plain stores -> L2 write-combining).
__global__ __launch_bounds__(256) void pgs_kernel(
    const float* __restrict__ priors, const float* __restrict__ s_prev,
    const int* __restrict__ mask, float* __restrict__ g,
    float* __restrict__ s_cur, float* __restrict__ outP, int first)
{
    const int blk  = blockIdx.x;
    const int b    = blk >> 7;
    const int k8   = (blk & 127) * 8;
    const int w    = threadIdx.x >> 6;
    const int lane = threadIdx.x & 63;

    __shared__ float red[4][768];
    __shared__ float pstage[48];

    float vv[12];
    {
        float sp[12];
#pragma unroll
        for (int s = 0; s < 12; ++s) sp[s] = s_prev[b * NN + s * 64 + lane];
        squash_regs(sp, vv, lane);
    }

    float sacc[12];
#pragma unroll
    for (int s = 0; s < 12; ++s) sacc[s] = 0.f;

#pragma unroll
    for (int r = 0; r < 2; ++r) {
        const int k = k8 + w * 2 + r;
        const long rid = (long)b * KK + k;
        const float* pr = priors + rid * NN;
        float pp[12];
#pragma unroll
        for (int s = 0; s < 12; ++s) pp[s] = pr[s * 64 + lane];

        float d[6];
#pragma unroll
        for (int o = 0; o < 6; ++o) {
            float t = pp[2*o] * vv[2*o] + pp[2*o+1] * vv[2*o+1];
#pragma unroll
            for (int off = 32; off > 0; off >>= 1) t += __shfl_xor(t, off, 64);
            d[o] = t;
        }

        if (first) {
            if (lane < 6) {
                float x = d[0];
#pragma unroll
                for (int o = 1; o < 6; ++o) if (lane == o) x = d[o];
                g[rid * 6 + lane] = x;
            }
        } else {
#pragma unroll
            for (int o = 0; o < 6; ++o) d[o] += g[rid * 6 + o];
        }

        float p[6];
        if (mask[rid] != 0) {
#pragma unroll
            for (int o = 0; o < 6; ++o) p[o] = 1.0f / 6.0f;
        } else {
            float m = d[0];
#pragma unroll
            for (int o = 1; o < 6; ++o) m = fmaxf(m, d[o]);
            float ssum = 0.f;
#pragma unroll
            for (int o = 0; o < 6; ++o) { p[o] = expf(d[o] - m); ssum += p[o]; }
            const float inv = 1.0f / ssum;
#pragma unroll
            for (int o = 0; o < 6; ++o) p[o] *= inv;
        }

        if (outP && lane < 6) {
            float x = p[0];
#pragma unroll
            for (int o = 1; o < 6; ++o) if (lane == o) x = p[o];
            pstage[(w * 2 + r) * 6 + lane] = x;
        }

#pragma unroll
        for (int s = 0; s < 12; ++s) sacc[s] = fmaf(p[s >> 1], pp[s], sacc[s]);
    }

#pragma unroll
    for (int s = 0; s < 12; ++s) red[w][s * 64 + lane] = sacc[s];
    __syncthreads();
    const int t = threadIdx.x;
#pragma unroll
    for (int i = 0; i < 3; ++i) {
        const int flat = t + i * 256;
        atomicAdd(&s_cur[b * NN + flat],
                  red[0][flat] + red[1][flat] + red[2][flat] + red[3][flat]);
    }

    if (outP) {
        // broadcast this block's 48 probs (8 k x 6 o) to all 1024 l positions.
        float* base = outP + (long)b * (LL * KK * OO) + k8 * 6;
        const int j = t & 3;
        const int lsub = t >> 2;
        const float4 c0 = *(const float4*)(pstage + j * 12);
        const float4 c1 = *(const float4*)(pstage + j * 12 + 4);
        const float4 c2 = *(const float4*)(pstage + j * 12 + 8);
#pragma unroll
        for (int lg = 0; lg < 16; ++lg) {
            float* dst = base + (long)(lg * 64 + lsub) * (KK * OO) + j * 12;
            *(float4*)(dst)     = c0;
            *(float4*)(dst + 4) = c1;
            *(float4*)(dst + 8) = c2;
        }
    }
}

// ---------------------------------------------------------------------------
// Output V-section: squash(s2) broadcast over L. grid 2048.
__global__ __launch_bounds__(256) void bcast_v_kernel(
    const float* __restrict__ s2, float* __restrict__ out)
{
    const int blk = blockIdx.x;
    const int b  = blk >> 8;
    const int l0 = (blk & 255) * 4;
    const int w = threadIdx.x >> 6, lane = threadIdx.x & 63;
    __shared__ float vrow[768];
    if (w == 0) {
        float sp[12], vvv[12];
#pragma unroll
        for (int s = 0; s < 12; ++s) sp[s] = s2[b * NN + s * 64 + lane];
        squash_regs(sp, vvv, lane);
#pragma unroll
        for (int s = 0; s < 12; ++s) vrow[s * 64 + lane] = vvv[s];
    }
    __syncthreads();
    float* dst = out + ((long)b * LL + l0) * NN;
    const int t = threadIdx.x;
#pragma unroll
    for (int i = 0; i < 3; ++i) {
        const int idx = t * 12 + i * 4;
        *(float4*)(dst + idx) = *(const float4*)(vrow + (idx % NN));
    }
}

// ---------------------------------------------------------------------------
extern "C" void kernel_launch(void* const* d_in, const int* in_sizes, int n_in,
                              void* d_out, int out_size, void* d_ws, size_t ws_size,
                              hipStream_t stream)
{
    (void)in_sizes; (void)n_in; (void)out_size; (void)ws_size;
    const float* u    = (const float*)d_in[0];
    const float* W    = (const float*)d_in[2];
    const int*   mask = (const int*)d_in[3];
    float*       out  = (float*)d_out;

    char* ws = (char*)d_ws;
    size_t off = 0;
    float*  priors = (float*)(ws + off);  off += (size_t)8192 * NN * 4;
    bf16_t* Ah     = (bf16_t*)(ws + off); off += (size_t)8192 * DD * 2;
    bf16_t* Al     = (bf16_t*)(ws + off); off += (size_t)8192 * DD * 2;
    bf16_t* Wth    = (bf16_t*)(ws + off); off += (size_t)OO * EE * DD * 2;
    bf16_t* Wtl    = (bf16_t*)(ws + off); off += (size_t)OO * EE * DD * 2;
    float*  g      = (float*)(ws + off);  off += (size_t)BB * KK * OO * 4;
    float*  sbuf   = (float*)(ws + off);  off += (size_t)3 * BB * NN * 4;
    float*  s0 = sbuf, *s1 = sbuf + BB * NN, *s2 = sbuf + 2 * BB * NN;

    const long NVF = (long)BB * LL * OO * EE;   // V-section size = 6,291,456

    hipLaunchKernelGGL(prep_kernel, dim3(8969), dim3(256), 0, stream,
                       u, Ah, Al, W, Wth, Wtl, sbuf);
    hipLaunchKernelGGL(gemm_priors, dim3(768), dim3(256), 0, stream,
                       Ah, Al, Wth, Wtl, priors, s0);
    hipLaunchKernelGGL(pgs_kernel, dim3(1024), dim3(256), 0, stream,
                       priors, s0, mask, g, s1, (float*)nullptr, 1);
    hipLaunchKernelGGL(pgs_kernel, dim3(1024), dim3(256), 0, stream,
                       priors, s1, mask, g, s2, out + NVF, 0);
    hipLaunchKernelGGL(bcast_v_kernel, dim3(2048), dim3(256), 0, stream,
                       s2, out);
}